// Round 1
// baseline (227.664 us; speedup 1.0000x reference)
//
#include <hip/hip_runtime.h>
#include <math.h>

#define NPTS     128
#define DIM      512
#define NPAIR    8128
#define NTRI     341376
#define ROW_PAIR0 128
#define ROW_TRI0  8256     // 128 + 8128
#define NROWS    349632    // 128 + 8128 + 341376
#define FILL_BLOCKS 43704  // NROWS * 32 float4 / 256 threads

// Kernel A: pairwise distances. One block per point i, one thread per point j.
// f64 accumulation of sum (wi-wj)^2 -> essentially exact d, minimizing
// boundary-flip risk on d <= 32.0.
__global__ void vr_dist_kernel(const float* __restrict__ W,
                               float* __restrict__ sigval,
                               unsigned long long* __restrict__ adj) {
    __shared__ float wi[DIM];
    const int i = blockIdx.x;
    const int j = threadIdx.x;
    for (int c = j; c < DIM; c += 128) wi[c] = W[i * DIM + c];
    __syncthreads();

    const float4* wj4 = (const float4*)(W + (size_t)j * DIM);
    const float4* wi4 = (const float4*)wi;
    double acc = 0.0;
    #pragma unroll 4
    for (int c = 0; c < DIM / 4; ++c) {
        float4 a = wi4[c];
        float4 b = wj4[c];
        double d0 = (double)a.x - (double)b.x;
        double d1 = (double)a.y - (double)b.y;
        double d2 = (double)a.z - (double)b.z;
        double d3 = (double)a.w - (double)b.w;
        acc = fma(d0, d0, acc);
        acc = fma(d1, d1, acc);
        acc = fma(d2, d2, acc);
        acc = fma(d3, d3, acc);
    }
    double dist = sqrt(acc);

    // adjacency bitmask: bit j of row i (two u64 per row; wave = 64 lanes)
    unsigned long long m = __ballot(dist <= 32.0);
    if ((j & 63) == 0) adj[i * 2 + (j >> 6)] = m;

    // sigmoid values for upper-triangle pairs, triu order
    if (j > i) {
        int p = 127 * i - ((i * (i - 1)) >> 1) + (j - i - 1);
        float x = 10.0f * (32.0f - (float)dist);
        sigval[p] = 1.0f / (1.0f + expf(-x));
    }
}

// Kernel B: fill the 349632 x 128 output. One float4 per thread; 8 rows per
// 256-thread block, so every block lies entirely in one segment.
__global__ __launch_bounds__(256) void vr_fill_kernel(
    const float* __restrict__ sigval,
    const unsigned long long* __restrict__ adj,
    float4* __restrict__ out) {
    __shared__ unsigned long long sadj[256];
    const int tid = threadIdx.x;
    sadj[tid] = adj[tid];
    __syncthreads();

    const int g   = blockIdx.x * 256 + tid;   // float4 index, < 2^24
    const int row = g >> 5;
    const int c0  = (g & 31) << 2;            // first of 4 columns

    float4 v = make_float4(0.f, 0.f, 0.f, 0.f);
    float* vp = (float*)&v;

    if (row < ROW_PAIR0) {
        // identity
        int d = row - c0;
        if (d >= 0 && d < 4) vp[d] = 1.0f;
    } else if (row < ROW_TRI0) {
        // pair rows: decode p -> (i, j), triu row-major order
        int p = row - ROW_PAIR0;
        int lo = 0, hi = 127;
        #pragma unroll
        for (int it = 0; it < 7; ++it) {
            int m = (lo + hi + 1) >> 1;
            int C = 127 * m - ((m * (m - 1)) >> 1);   // #pairs with first < m
            if (C <= p) lo = m; else hi = m - 1;
        }
        int i = lo;
        int j = i + 1 + (p - (127 * i - ((i * (i - 1)) >> 1)));
        float val = sigval[p];
        int di = i - c0, dj = j - c0;
        if (di >= 0 && di < 4) vp[di] = val;
        if (dj >= 0 && dj < 4) vp[dj] = val;
    } else {
        // triple rows: decode t -> (a, b, c), lexicographic combinations
        int t = row - ROW_TRI0;
        int lo = 0, hi = 125;
        #pragma unroll
        for (int it = 0; it < 7; ++it) {
            int m = (lo + hi + 1) >> 1;
            int rem = NPTS - m;
            int T = NTRI - rem * (rem - 1) * (rem - 2) / 6;  // #triples first < m
            if (T <= t) lo = m; else hi = m - 1;
        }
        int a = lo;
        int rema = NPTS - a;
        int r = t - (NTRI - rema * (rema - 1) * (rema - 2) / 6);
        lo = a + 1; hi = 126;
        #pragma unroll
        for (int it = 0; it < 7; ++it) {
            int m = (lo + hi + 1) >> 1;
            int C2 = ((m - a - 1) * (254 - a - m)) >> 1;  // #pairs with 2nd < m
            if (C2 <= r) lo = m; else hi = m - 1;
        }
        int b = lo;
        int c = b + 1 + (r - (((b - a - 1) * (254 - a - b)) >> 1));

        unsigned long long bab = sadj[(a << 1) + (b >> 6)] >> (b & 63);
        unsigned long long bbc = sadj[(b << 1) + (c >> 6)] >> (c & 63);
        unsigned long long bac = sadj[(a << 1) + (c >> 6)] >> (c & 63);
        float cond = (float)(bab & bbc & bac & 1ull);

        int da = a - c0, db = b - c0, dc = c - c0;
        if (da >= 0 && da < 4) vp[da] = cond;
        if (db >= 0 && db < 4) vp[db] = cond;
        if (dc >= 0 && dc < 4) vp[dc] = cond;
    }
    out[g] = v;
}

extern "C" void kernel_launch(void* const* d_in, const int* in_sizes, int n_in,
                              void* d_out, int out_size, void* d_ws, size_t ws_size,
                              hipStream_t stream) {
    const float* W = (const float*)d_in[0];
    float* out = (float*)d_out;

    // workspace layout: adj (256 u64 = 2048 B) | sigval (8128 f32)
    unsigned long long* adj = (unsigned long long*)d_ws;
    float* sigval = (float*)((char*)d_ws + 2048);

    vr_dist_kernel<<<128, 128, 0, stream>>>(W, sigval, adj);
    vr_fill_kernel<<<FILL_BLOCKS, 256, 0, stream>>>(sigval, adj, (float4*)out);
}

// Round 3
// 202.031 us; speedup vs baseline: 1.1269x; 1.1269x over previous
//
#include <hip/hip_runtime.h>
#include <math.h>

#define NPTS      128
#define DIM       512
#define NPAIR     8128
#define NTRI      341376
#define ROW_PAIR0 128
#define ROW_TRI0  8256     // 128 + 8128
#define NROWS     349632   // 128 + 8128 + 341376
#define FILL_BLOCKS 1366   // ceil(NROWS / 256)

typedef float vfloat4 __attribute__((ext_vector_type(4)));  // native clang vec

// Kernel A: pairwise distances. One block per point i, one thread per point j.
// f64 accumulation (4 independent chains) -> essentially exact d, minimizing
// boundary-flip risk on d <= 32.0.
__global__ void vr_dist_kernel(const float* __restrict__ W,
                               float* __restrict__ sigval,
                               unsigned long long* __restrict__ adj) {
    __shared__ float wi[DIM];
    const int i = blockIdx.x;
    const int j = threadIdx.x;
    for (int c = j; c < DIM; c += 128) wi[c] = W[i * DIM + c];
    __syncthreads();

    const float4* wj4 = (const float4*)(W + (size_t)j * DIM);
    const float4* wi4 = (const float4*)wi;
    double a0 = 0.0, a1 = 0.0, a2 = 0.0, a3 = 0.0;
    #pragma unroll 4
    for (int c = 0; c < DIM / 4; ++c) {
        float4 a = wi4[c];
        float4 b = wj4[c];
        double d0 = (double)a.x - (double)b.x;
        double d1 = (double)a.y - (double)b.y;
        double d2 = (double)a.z - (double)b.z;
        double d3 = (double)a.w - (double)b.w;
        a0 = fma(d0, d0, a0);
        a1 = fma(d1, d1, a1);
        a2 = fma(d2, d2, a2);
        a3 = fma(d3, d3, a3);
    }
    double dist = sqrt((a0 + a1) + (a2 + a3));

    // adjacency bitmask: bit j of row i (two u64 per row; wave = 64 lanes)
    unsigned long long m = __ballot(dist <= 32.0);
    if ((j & 63) == 0) adj[i * 2 + (j >> 6)] = m;

    // sigmoid values for upper-triangle pairs, triu order
    if (j > i) {
        int p = 127 * i - ((i * (i - 1)) >> 1) + (j - i - 1);
        float x = 10.0f * (32.0f - (float)dist);
        sigval[p] = 1.0f / (1.0f + expf(-x));
    }
}

// Kernel B: fill the 349632 x 128 output.
// Phase 1: each of the 256 threads decodes ONE row (binary searches happen
//          once per row, not once per float4) -> LDS entry {cols packed, val}.
// Phase 2: 32 coalesced nontemporal-store sweeps (~20 VALU per 16 B).
__global__ __launch_bounds__(256) void vr_fill_kernel(
    const float* __restrict__ sigval,
    const unsigned long long* __restrict__ adj,
    vfloat4* __restrict__ out) {
    __shared__ unsigned long long sadj[256];
    __shared__ int   spack[256];
    __shared__ float sval[256];

    const int tid = threadIdx.x;
    sadj[tid] = adj[tid];
    __syncthreads();

    const int row0 = blockIdx.x * 256;
    const int row  = row0 + tid;

    // ---- Phase 1: decode one row per thread ----
    int   pack = 255 | (255 << 8) | (255 << 16);  // all-sentinel
    float val  = 0.0f;
    if (row < ROW_PAIR0) {
        pack = row | (255 << 8) | (255 << 16);
        val  = 1.0f;
    } else if (row < ROW_TRI0) {
        int p = row - ROW_PAIR0;
        int lo = 0, hi = 127;
        #pragma unroll
        for (int it = 0; it < 7; ++it) {
            int m = (lo + hi + 1) >> 1;
            int C = 127 * m - ((m * (m - 1)) >> 1);
            if (C <= p) lo = m; else hi = m - 1;
        }
        int i = lo;
        int j = i + 1 + (p - (127 * i - ((i * (i - 1)) >> 1)));
        pack = i | (j << 8) | (255 << 16);
        val  = sigval[p];
    } else if (row < NROWS) {
        int t = row - ROW_TRI0;
        int lo = 0, hi = 125;
        #pragma unroll
        for (int it = 0; it < 7; ++it) {
            int m = (lo + hi + 1) >> 1;
            int rem = NPTS - m;
            int T = NTRI - rem * (rem - 1) * (rem - 2) / 6;
            if (T <= t) lo = m; else hi = m - 1;
        }
        int a = lo;
        int rema = NPTS - a;
        int r = t - (NTRI - rema * (rema - 1) * (rema - 2) / 6);
        lo = a + 1; hi = 126;
        #pragma unroll
        for (int it = 0; it < 7; ++it) {
            int m = (lo + hi + 1) >> 1;
            int C2 = ((m - a - 1) * (254 - a - m)) >> 1;
            if (C2 <= r) lo = m; else hi = m - 1;
        }
        int b = lo;
        int c = b + 1 + (r - (((b - a - 1) * (254 - a - b)) >> 1));

        unsigned long long bab = sadj[(a << 1) + (b >> 6)] >> (b & 63);
        unsigned long long bbc = sadj[(b << 1) + (c >> 6)] >> (c & 63);
        unsigned long long bac = sadj[(a << 1) + (c >> 6)] >> (c & 63);
        val  = (float)(bab & bbc & bac & 1ull);
        pack = a | (b << 8) | (c << 16);
    }
    spack[tid] = pack;
    sval[tid]  = val;
    __syncthreads();

    // ---- Phase 2: 32 coalesced write sweeps (8 rows per sweep) ----
    const int col4 = tid & 31;          // which float4 within the row
    const int c0   = col4 << 2;         // first column of this float4
    const int rsub = tid >> 5;          // 0..7

    #pragma unroll 4
    for (int k = 0; k < 32; ++k) {
        int rl = (k << 3) + rsub;       // local row 0..255
        int pk = spack[rl];
        float vv = sval[rl];
        int a = pk & 255, b = (pk >> 8) & 255, c = (pk >> 16) & 255;

        vfloat4 v;
        v.x = (a == c0     || b == c0     || c == c0    ) ? vv : 0.0f;
        v.y = (a == c0 + 1 || b == c0 + 1 || c == c0 + 1) ? vv : 0.0f;
        v.z = (a == c0 + 2 || b == c0 + 2 || c == c0 + 2) ? vv : 0.0f;
        v.w = (a == c0 + 3 || b == c0 + 3 || c == c0 + 3) ? vv : 0.0f;

        int grow = row0 + rl;
        if (grow < NROWS)
            __builtin_nontemporal_store(v, &out[(size_t)grow * 32 + col4]);
    }
}

extern "C" void kernel_launch(void* const* d_in, const int* in_sizes, int n_in,
                              void* d_out, int out_size, void* d_ws, size_t ws_size,
                              hipStream_t stream) {
    const float* W = (const float*)d_in[0];
    float* out = (float*)d_out;

    // workspace layout: adj (256 u64 = 2048 B) | sigval (8128 f32)
    unsigned long long* adj = (unsigned long long*)d_ws;
    float* sigval = (float*)((char*)d_ws + 2048);

    vr_dist_kernel<<<128, 128, 0, stream>>>(W, sigval, adj);
    vr_fill_kernel<<<FILL_BLOCKS, 256, 0, stream>>>(sigval, adj, (vfloat4*)out);
}

// Round 4
// 191.810 us; speedup vs baseline: 1.1869x; 1.0533x over previous
//
#include <hip/hip_runtime.h>
#include <math.h>

#define NPTS      128
#define DIM       512
#define NPAIR     8128
#define NTRI      341376
#define ROW_PAIR0 128
#define ROW_TRI0  8256     // 128 + 8128
#define NROWS     349632   // 128 + 8128 + 341376
#define FILL_BLOCKS 1366   // ceil(NROWS / 256)

// Kernel A: pairwise distances. One block per point i, one thread per point j.
// f64 accumulation (4 independent chains) -> essentially exact d, minimizing
// boundary-flip risk on d <= 32.0.
__global__ void vr_dist_kernel(const float* __restrict__ W,
                               float* __restrict__ sigval,
                               unsigned long long* __restrict__ adj) {
    __shared__ float wi[DIM];
    const int i = blockIdx.x;
    const int j = threadIdx.x;
    for (int c = j; c < DIM; c += 128) wi[c] = W[i * DIM + c];
    __syncthreads();

    const float4* wj4 = (const float4*)(W + (size_t)j * DIM);
    const float4* wi4 = (const float4*)wi;
    double a0 = 0.0, a1 = 0.0, a2 = 0.0, a3 = 0.0;
    #pragma unroll 4
    for (int c = 0; c < DIM / 4; ++c) {
        float4 a = wi4[c];
        float4 b = wj4[c];
        double d0 = (double)a.x - (double)b.x;
        double d1 = (double)a.y - (double)b.y;
        double d2 = (double)a.z - (double)b.z;
        double d3 = (double)a.w - (double)b.w;
        a0 = fma(d0, d0, a0);
        a1 = fma(d1, d1, a1);
        a2 = fma(d2, d2, a2);
        a3 = fma(d3, d3, a3);
    }
    double dist = sqrt((a0 + a1) + (a2 + a3));

    // adjacency bitmask: bit j of row i (two u64 per row; wave = 64 lanes)
    unsigned long long m = __ballot(dist <= 32.0);
    if ((j & 63) == 0) adj[i * 2 + (j >> 6)] = m;

    // sigmoid values for upper-triangle pairs, triu order
    if (j > i) {
        int p = 127 * i - ((i * (i - 1)) >> 1) + (j - i - 1);
        float x = 10.0f * (32.0f - (float)dist);
        sigval[p] = 1.0f / (1.0f + expf(-x));
    }
}

// Kernel B: fill the 349632 x 128 output.
// Phase 1: each of the 256 threads decodes ONE row -> LDS {cols packed, val}.
// Phase 2: 32 coalesced float4-store sweeps. Plain stores (L2-routed) — the
//          nt flag bypassed L2 write-combining and cost ~2.5x on write BW.
__global__ __launch_bounds__(256) void vr_fill_kernel(
    const float* __restrict__ sigval,
    const unsigned long long* __restrict__ adj,
    float4* __restrict__ out) {
    __shared__ unsigned long long sadj[256];
    __shared__ int   spack[256];
    __shared__ float sval[256];

    const int tid = threadIdx.x;
    sadj[tid] = adj[tid];
    __syncthreads();

    const int row0 = blockIdx.x * 256;
    const int row  = row0 + tid;

    // ---- Phase 1: decode one row per thread ----
    int   pack = 255 | (255 << 8) | (255 << 16);  // all-sentinel
    float val  = 0.0f;
    if (row < ROW_PAIR0) {
        pack = row | (255 << 8) | (255 << 16);
        val  = 1.0f;
    } else if (row < ROW_TRI0) {
        int p = row - ROW_PAIR0;
        int lo = 0, hi = 127;
        #pragma unroll
        for (int it = 0; it < 7; ++it) {
            int m = (lo + hi + 1) >> 1;
            int C = 127 * m - ((m * (m - 1)) >> 1);
            if (C <= p) lo = m; else hi = m - 1;
        }
        int i = lo;
        int j = i + 1 + (p - (127 * i - ((i * (i - 1)) >> 1)));
        pack = i | (j << 8) | (255 << 16);
        val  = sigval[p];
    } else if (row < NROWS) {
        int t = row - ROW_TRI0;
        int lo = 0, hi = 125;
        #pragma unroll
        for (int it = 0; it < 7; ++it) {
            int m = (lo + hi + 1) >> 1;
            int rem = NPTS - m;
            int T = NTRI - rem * (rem - 1) * (rem - 2) / 6;
            if (T <= t) lo = m; else hi = m - 1;
        }
        int a = lo;
        int rema = NPTS - a;
        int r = t - (NTRI - rema * (rema - 1) * (rema - 2) / 6);
        lo = a + 1; hi = 126;
        #pragma unroll
        for (int it = 0; it < 7; ++it) {
            int m = (lo + hi + 1) >> 1;
            int C2 = ((m - a - 1) * (254 - a - m)) >> 1;
            if (C2 <= r) lo = m; else hi = m - 1;
        }
        int b = lo;
        int c = b + 1 + (r - (((b - a - 1) * (254 - a - b)) >> 1));

        unsigned long long bab = sadj[(a << 1) + (b >> 6)] >> (b & 63);
        unsigned long long bbc = sadj[(b << 1) + (c >> 6)] >> (c & 63);
        unsigned long long bac = sadj[(a << 1) + (c >> 6)] >> (c & 63);
        val  = (float)(bab & bbc & bac & 1ull);
        pack = a | (b << 8) | (c << 16);
    }
    spack[tid] = pack;
    sval[tid]  = val;
    __syncthreads();

    // ---- Phase 2: 32 coalesced write sweeps (8 rows per sweep) ----
    const int col4 = tid & 31;          // which float4 within the row
    const int c0   = col4 << 2;         // first column of this float4
    const int rsub = tid >> 5;          // 0..7

    #pragma unroll 4
    for (int k = 0; k < 32; ++k) {
        int rl = (k << 3) + rsub;       // local row 0..255
        int pk = spack[rl];
        float vv = sval[rl];
        int a = pk & 255, b = (pk >> 8) & 255, c = (pk >> 16) & 255;

        float4 v;
        v.x = (a == c0     || b == c0     || c == c0    ) ? vv : 0.0f;
        v.y = (a == c0 + 1 || b == c0 + 1 || c == c0 + 1) ? vv : 0.0f;
        v.z = (a == c0 + 2 || b == c0 + 2 || c == c0 + 2) ? vv : 0.0f;
        v.w = (a == c0 + 3 || b == c0 + 3 || c == c0 + 3) ? vv : 0.0f;

        int grow = row0 + rl;
        if (grow < NROWS)
            out[(size_t)grow * 32 + col4] = v;
    }
}

extern "C" void kernel_launch(void* const* d_in, const int* in_sizes, int n_in,
                              void* d_out, int out_size, void* d_ws, size_t ws_size,
                              hipStream_t stream) {
    const float* W = (const float*)d_in[0];
    float* out = (float*)d_out;

    // workspace layout: adj (256 u64 = 2048 B) | sigval (8128 f32)
    unsigned long long* adj = (unsigned long long*)d_ws;
    float* sigval = (float*)((char*)d_ws + 2048);

    vr_dist_kernel<<<128, 128, 0, stream>>>(W, sigval, adj);
    vr_fill_kernel<<<FILL_BLOCKS, 256, 0, stream>>>(sigval, adj, (float4*)out);
}